// Round 2
// baseline (720.387 us; speedup 1.0000x reference)
//
#include <hip/hip_runtime.h>
#include <hip/hip_bf16.h>
#include <cstdint>
#include <cstddef>

// Problem constants (match reference)
#define B_TOT   2048
#define N_LIN   64
#define D_DIM   256
#define NSTEPS  4      // n_recurs + 1
#define BT      64     // batch rows per block

typedef __attribute__((ext_vector_type(8))) short short8;   // 8 bf16 = 4 VGPR
typedef __attribute__((ext_vector_type(4))) float f32x4;    // MFMA accumulator

// Split fp32 -> bf16 hi + bf16 lo (RNE both).  hi+lo reproduces f to ~2^-17 rel.
__device__ __forceinline__ void split2(float f, unsigned short& h, unsigned short& l) {
    unsigned u = __float_as_uint(f);
    unsigned r = u + 0x7FFFu + ((u >> 16) & 1u);
    h = (unsigned short)(r >> 16);
    float hf = __uint_as_float(r & 0xFFFF0000u);
    float rem = f - hf;
    unsigned u2 = __float_as_uint(rem);
    unsigned r2 = u2 + 0x7FFFu + ((u2 >> 16) & 1u);
    l = (unsigned short)(r2 >> 16);
}

__device__ __forceinline__ float bf16_to_f(unsigned short s) {
    return __uint_as_float((unsigned)s << 16);
}

// ---------------------------------------------------------------------------
// Prep (fast path only): masked weights -> bf16 hi/lo split arrays in d_ws.
// ---------------------------------------------------------------------------
__global__ void prep_kernel(const float* __restrict__ w, const float* __restrict__ wm,
                            unsigned short* __restrict__ w_hi,
                            unsigned short* __restrict__ w_lo) {
    const int nW4 = N_LIN * D_DIM * D_DIM / 4;   // 1,048,576 float4 groups
    int stride = gridDim.x * blockDim.x;
    for (int i = blockIdx.x * blockDim.x + threadIdx.x; i < nW4; i += stride) {
        float4 wv = ((const float4*)w)[i];
        float4 mv = ((const float4*)wm)[i];
        ushort4 h, l;
        split2(wv.x * mv.x, h.x, l.x);
        split2(wv.y * mv.y, h.y, l.y);
        split2(wv.z * mv.z, h.z, l.z);
        split2(wv.w * mv.w, h.w, l.w);
        ((ushort4*)w_hi)[i] = h;
        ((ushort4*)w_lo)[i] = l;
    }
}

// ---------------------------------------------------------------------------
// Fused 4-step recurrence.  One block = 64 batch rows x one linear n.
// x lives in LDS as bf16 hi/lo (swizzled, 64 KB total).
//
// v-next vs previous: latency-bound fix — 512 threads / 8 waves per block
// (same 64 KB LDS, 2 blocks/CU -> 16 waves/CU = 4 waves/SIMD, was 2).
// Wave (jg = wv&3, bh = wv>>2): bh halves the batch rows (2 bt tiles each),
// jg owns active j-tiles ROUND-ROBIN (jt = jg + 4u, u < u_cnt) so every wave
// has >=2 active j-tiles for any n_act (was: whole waves idle at n_act=128).
// acc shrinks to [4][2] (32 VGPR) giving the scheduler register headroom.
// ---------------------------------------------------------------------------
template <bool ONFLY>
__global__ __launch_bounds__(512, 4)
void fused_kernel(const float* __restrict__ xin,
                  const unsigned short* __restrict__ w_hi,
                  const unsigned short* __restrict__ w_lo,
                  const float* __restrict__ wraw,
                  const float* __restrict__ wmask,
                  const float* __restrict__ braw,
                  const float* __restrict__ bmask,
                  float* __restrict__ xout) {
    __shared__ unsigned short xh[BT * 256];   // 32 KB
    __shared__ unsigned short xl[BT * 256];   // 32 KB  (total = 64 KB)
    __shared__ int s_cnt[4];

    const int tid  = threadIdx.x;
    const int lane = tid & 63;
    const int wv   = tid >> 6;      // 0..7
    const int jg   = wv & 3;        // j-group: owns jt = jg + 4u
    const int bh   = wv >> 2;       // batch half: bt tiles {bh*2, bh*2+1}
    const int quad = lane >> 4;
    const int l16  = lane & 15;

    // XCD-aware swizzle: all 32 batch-tiles of a given n share blockIdx%8,
    // so each XCD's L2 only holds 8 n's worth of weights (2 MB < 4 MB).
    const int xcd = blockIdx.x & 7;
    const int j8  = blockIdx.x >> 3;         // 0..255
    const int n   = (xcd << 3) | (j8 & 7);   // 0..63
    const int btk = j8 >> 3;                 // 0..31

    const size_t row_stride = (size_t)N_LIN * D_DIM;  // 16384 floats between batch rows
    const float* xsrc = xin  + ((size_t)btk * BT * N_LIN + n) * D_DIM;
    float*       xdst = xout + ((size_t)btk * BT * N_LIN + n) * D_DIM;

    // ---- initial load: global fp32 -> LDS bf16 hi/lo (coalesced float4) ----
    for (int i = tid; i < BT * (D_DIM / 4); i += 512) {
        int r = i >> 6, c4 = i & 63;
        float4 v = ((const float4*)(xsrc + (size_t)r * row_stride))[c4];
        ushort4 h, l;
        split2(v.x, h.x, l.x);
        split2(v.y, h.y, l.y);
        split2(v.z, h.z, l.z);
        split2(v.w, h.w, l.w);
        int pi = r * 256 + ((((c4 >> 1) ^ (r & 7))) << 3) + ((c4 & 1) << 2);
        *((ushort4*)&xh[pi]) = h;
        *((ushort4*)&xl[pi]) = l;
    }

    // ---- runtime n_act from bias_mask (prefix-active structure) ----
    if (wv < 4) {
        float bv = bmask[n * D_DIM + wv * 64 + lane];
        unsigned long long actm = __ballot(bv != 0.0f);
        if (lane == 0) s_cnt[wv] = __popcll(actm);
    }

    // ---- per-lane masked bias: j = (jg+4u)*16 + quad*4 + rg ----
    float bias_r[4][4];
    #pragma unroll
    for (int u = 0; u < 4; ++u)
        #pragma unroll
        for (int rg = 0; rg < 4; ++rg) {
            int c = (jg + 4 * u) * 16 + quad * 4 + rg;
            bias_r[u][rg] = braw[n * D_DIM + c] * bmask[n * D_DIM + c];
        }

    float bmj[4];   // ONFLY: w-row (j) mask scalar per owned j-tile
    if (ONFLY) {
        #pragma unroll
        for (int u = 0; u < 4; ++u)
            bmj[u] = bmask[n * D_DIM + (jg + 4 * u) * 16 + l16];
    }

    // w-fragment base: lane covers w[j = (jg+4u)*16 + l16][i = kt*32 + quad*8 .. +7]
    const size_t wbase = ((size_t)n * D_DIM + (size_t)jg * 16 + l16) * D_DIM + (size_t)quad * 8;

    __syncthreads();

    const int n_act  = s_cnt[0] + s_cnt[1] + s_cnt[2] + s_cnt[3];   // {128..256}, mult of 32
    const int kt_lim = n_act >> 5;                                   // active k-tiles (4..8)
    const int njt    = n_act >> 4;                                   // active j-tiles (8..16)
    const int u_cnt  = (njt - jg + 3) >> 2;                          // owned tiles (2..4)

    #pragma unroll 1
    for (int step = 0; step < NSTEPS; ++step) {
        f32x4 acc[4][2];   // [u][v]: D[j = (jg+4u)*16+quad*4+rg][b = (bh*2+v)*16+l16]
        #pragma unroll
        for (int u = 0; u < 4; ++u)
            #pragma unroll
            for (int v = 0; v < 2; ++v)
                acc[u][v] = f32x4{0.f, 0.f, 0.f, 0.f};

        #pragma unroll 2
        for (int kt = 0; kt < kt_lim; ++kt) {
            // ---- w fragments (A operand) ----
            short8 wh[4], wl[4];
            if (!ONFLY) {
                #pragma unroll
                for (int u = 0; u < 4; ++u) if (u < u_cnt) {
                    size_t off = wbase + (size_t)u * 64 * D_DIM + (size_t)kt * 32;
                    wh[u] = *((const short8*)(w_hi + off));
                    wl[u] = *((const short8*)(w_lo + off));
                }
            } else {
                const float* bmi_p = bmask + n * D_DIM + kt * 32 + quad * 8;
                float4 mi0 = ((const float4*)bmi_p)[0];
                float4 mi1 = ((const float4*)bmi_p)[1];
                float mi[8] = {mi0.x, mi0.y, mi0.z, mi0.w, mi1.x, mi1.y, mi1.z, mi1.w};
                #pragma unroll
                for (int u = 0; u < 4; ++u) if (u < u_cnt) {
                    const float* wp = wraw + wbase + (size_t)u * 64 * D_DIM + (size_t)kt * 32;
                    float4 w0 = ((const float4*)wp)[0];
                    float4 w1 = ((const float4*)wp)[1];
                    float wvv[8] = {w0.x, w0.y, w0.z, w0.w, w1.x, w1.y, w1.z, w1.w};
                    #pragma unroll
                    for (int j = 0; j < 8; ++j) {
                        unsigned short h, l;
                        split2(wvv[j] * bmj[u] * mi[j], h, l);
                        wh[u][j] = (short)h;
                        wl[u][j] = (short)l;
                    }
                }
            }
            // ---- x fragments (B operand; LDS, swizzled) ----
            short8 xhf[2], xlf[2];
            #pragma unroll
            for (int v = 0; v < 2; ++v) {
                int m = (bh * 2 + v) * 16 + l16;
                int c0 = kt * 32 + quad * 8;
                int pi = m * 256 + ((((c0 >> 3) ^ (m & 7))) << 3);
                xhf[v] = *((const short8*)&xh[pi]);
                xlf[v] = *((const short8*)&xl[pi]);
            }
            #pragma unroll
            for (int u = 0; u < 4; ++u) if (u < u_cnt) {
                #pragma unroll
                for (int v = 0; v < 2; ++v) {
                    acc[u][v] = __builtin_amdgcn_mfma_f32_16x16x32_bf16(wh[u], xhf[v], acc[u][v], 0, 0, 0);
                    acc[u][v] = __builtin_amdgcn_mfma_f32_16x16x32_bf16(wh[u], xlf[v], acc[u][v], 0, 0, 0);
                    acc[u][v] = __builtin_amdgcn_mfma_f32_16x16x32_bf16(wl[u], xhf[v], acc[u][v], 0, 0, 0);
                }
            }
        }

        __syncthreads();   // all waves' x-reads done before x is overwritten

        const bool last = (step == NSTEPS - 1);
        #pragma unroll
        for (int u = 0; u < 4; ++u) {
            const bool act = (u < u_cnt);
            if (act || last) {
                #pragma unroll
                for (int v = 0; v < 2; ++v) {
                    int r  = (bh * 2 + v) * 16 + l16;             // batch row
                    int c0 = (jg + 4 * u) * 16 + quad * 4;        // 4 consecutive cols
                    int pi = r * 256 + ((((c0 >> 3) ^ (r & 7))) << 3) + (c0 & 7);
                    ushort4 oh = *((const ushort4*)&xh[pi]);      // ds_read_b64
                    ushort4 ol = *((const ushort4*)&xl[pi]);
                    float xn[4];
                    xn[0] = bf16_to_f(oh.x) + bf16_to_f(ol.x);
                    xn[1] = bf16_to_f(oh.y) + bf16_to_f(ol.y);
                    xn[2] = bf16_to_f(oh.z) + bf16_to_f(ol.z);
                    xn[3] = bf16_to_f(oh.w) + bf16_to_f(ol.w);
                    if (act) {
                        #pragma unroll
                        for (int rg = 0; rg < 4; ++rg)
                            xn[rg] += fmaxf(acc[u][v][rg] + bias_r[u][rg], 0.f);
                    }
                    if (last) {
                        float4 o;
                        o.x = xn[0]; o.y = xn[1]; o.z = xn[2]; o.w = xn[3];
                        *((float4*)(xdst + (size_t)r * row_stride + c0)) = o;  // dwordx4
                    } else if (act) {
                        ushort4 h, l;
                        split2(xn[0], h.x, l.x);
                        split2(xn[1], h.y, l.y);
                        split2(xn[2], h.z, l.z);
                        split2(xn[3], h.w, l.w);
                        *((ushort4*)&xh[pi]) = h;                 // ds_write_b64
                        *((ushort4*)&xl[pi]) = l;
                    }
                }
            }
        }
        __syncthreads();   // new x fully written before next step's reads
    }
}

// ---------------------------------------------------------------------------
extern "C" void kernel_launch(void* const* d_in, const int* in_sizes, int n_in,
                              void* d_out, int out_size, void* d_ws, size_t ws_size,
                              hipStream_t stream) {
    const float* x  = (const float*)d_in[0];
    const float* w  = (const float*)d_in[1];
    const float* b  = (const float*)d_in[2];
    const float* wm = (const float*)d_in[3];
    const float* bm = (const float*)d_in[4];
    float* out = (float*)d_out;

    const size_t needW = (size_t)2 * N_LIN * D_DIM * D_DIM * sizeof(unsigned short); // 16 MB
    const int grid = (B_TOT / BT) * N_LIN;   // 2048 blocks

    if (ws_size >= needW) {
        // Fast path: pre-split masked weights into workspace once per call.
        unsigned short* w_hi = (unsigned short*)d_ws;
        unsigned short* w_lo = w_hi + (size_t)N_LIN * D_DIM * D_DIM;
        prep_kernel<<<1024, 256, 0, stream>>>(w, wm, w_hi, w_lo);
        fused_kernel<false><<<grid, 512, 0, stream>>>(x, w_hi, w_lo, w, wm, b, bm, out);
    } else {
        // Fallback: no scratch — mask+split W on the fly inside the kernel.
        fused_kernel<true><<<grid, 512, 0, stream>>>(x, nullptr, nullptr, w, wm, b, bm, out);
    }
}

// Round 3
// 477.839 us; speedup vs baseline: 1.5076x; 1.5076x over previous
//
#include <hip/hip_runtime.h>
#include <hip/hip_bf16.h>
#include <cstdint>
#include <cstddef>

// Problem constants (match reference)
#define B_TOT   2048
#define N_LIN   64
#define D_DIM   256
#define NSTEPS  4      // n_recurs + 1
#define BT      64     // batch rows per block

typedef __attribute__((ext_vector_type(8))) short short8;   // 8 bf16 = 4 VGPR
typedef __attribute__((ext_vector_type(4))) float f32x4;    // MFMA accumulator

// Split fp32 -> bf16 hi + bf16 lo (RNE both).  hi+lo reproduces f to ~2^-17 rel.
__device__ __forceinline__ void split2(float f, unsigned short& h, unsigned short& l) {
    unsigned u = __float_as_uint(f);
    unsigned r = u + 0x7FFFu + ((u >> 16) & 1u);
    h = (unsigned short)(r >> 16);
    float hf = __uint_as_float(r & 0xFFFF0000u);
    float rem = f - hf;
    unsigned u2 = __float_as_uint(rem);
    unsigned r2 = u2 + 0x7FFFu + ((u2 >> 16) & 1u);
    l = (unsigned short)(r2 >> 16);
}

__device__ __forceinline__ float bf16_to_f(unsigned short s) {
    return __uint_as_float((unsigned)s << 16);
}

// ---------------------------------------------------------------------------
// Prep (fast path only): masked weights -> bf16 hi/lo split arrays in d_ws.
// ---------------------------------------------------------------------------
__global__ void prep_kernel(const float* __restrict__ w, const float* __restrict__ wm,
                            unsigned short* __restrict__ w_hi,
                            unsigned short* __restrict__ w_lo) {
    const int nW4 = N_LIN * D_DIM * D_DIM / 4;   // 1,048,576 float4 groups
    int stride = gridDim.x * blockDim.x;
    for (int i = blockIdx.x * blockDim.x + threadIdx.x; i < nW4; i += stride) {
        float4 wv = ((const float4*)w)[i];
        float4 mv = ((const float4*)wm)[i];
        ushort4 h, l;
        split2(wv.x * mv.x, h.x, l.x);
        split2(wv.y * mv.y, h.y, l.y);
        split2(wv.z * mv.z, h.z, l.z);
        split2(wv.w * mv.w, h.w, l.w);
        ((ushort4*)w_hi)[i] = h;
        ((ushort4*)w_lo)[i] = l;
    }
}

// ---------------------------------------------------------------------------
// Fused 4-step recurrence.  One block = 64 batch rows x one linear n.
// x lives in LDS as bf16 hi/lo (swizzled, 64 KB); 512 threads / 8 waves.
//
// v-next vs previous round:
//  * j-tiles split round-robin over ALL 8 waves (wave owns jt = wv, wv+8;
//    all 4 batch tiles) -> no duplicated w-loads across waves (round-2's bh
//    split doubled L2 traffic), per-wave MFMA:load ratio same as round 1,
//    but 4 waves/SIMD instead of 2 to hide latency.
//  * register-lean (~105 VGPR target, fits 4 waves/SIMD under 128) with
//    EXPLICIT software pipelining: two named w-fragment buffer sets A/B
//    (static indexing only), hand-unrolled pairwise k-loop prefetching
//    kt+1 while MFMA'ing kt; next step's kt=0 load issued before the
//    epilogue barrier so L2 latency hides under epilogue VALU.
// ---------------------------------------------------------------------------
template <bool ONFLY>
__global__ __launch_bounds__(512, 4)
void fused_kernel(const float* __restrict__ xin,
                  const unsigned short* __restrict__ w_hi,
                  const unsigned short* __restrict__ w_lo,
                  const float* __restrict__ wraw,
                  const float* __restrict__ wmask,
                  const float* __restrict__ braw,
                  const float* __restrict__ bmask,
                  float* __restrict__ xout) {
    __shared__ unsigned short xh[BT * 256];   // 32 KB
    __shared__ unsigned short xl[BT * 256];   // 32 KB  (total = 64 KB)
    __shared__ int s_cnt[4];

    const int tid  = threadIdx.x;
    const int lane = tid & 63;
    const int wvid = tid >> 6;      // 0..7: owns j-tiles {wvid, wvid+8}
    const int quad = lane >> 4;
    const int l16  = lane & 15;

    // XCD-aware swizzle: all 32 batch-tiles of a given n share blockIdx%8,
    // so each XCD's L2 only holds 8 n's worth of weights (2 MB < 4 MB).
    const int xcd = blockIdx.x & 7;
    const int j8  = blockIdx.x >> 3;         // 0..255
    const int n   = (xcd << 3) | (j8 & 7);   // 0..63
    const int btk = j8 >> 3;                 // 0..31

    const size_t row_stride = (size_t)N_LIN * D_DIM;  // 16384 floats between batch rows
    const float* xsrc = xin  + ((size_t)btk * BT * N_LIN + n) * D_DIM;
    float*       xdst = xout + ((size_t)btk * BT * N_LIN + n) * D_DIM;

    // ---- initial load: global fp32 -> LDS bf16 hi/lo (coalesced float4) ----
    for (int i = tid; i < BT * (D_DIM / 4); i += 512) {
        int r = i >> 6, c4 = i & 63;
        float4 v = ((const float4*)(xsrc + (size_t)r * row_stride))[c4];
        ushort4 h, l;
        split2(v.x, h.x, l.x);
        split2(v.y, h.y, l.y);
        split2(v.z, h.z, l.z);
        split2(v.w, h.w, l.w);
        int pi = r * 256 + ((((c4 >> 1) ^ (r & 7))) << 3) + ((c4 & 1) << 2);
        *((ushort4*)&xh[pi]) = h;
        *((ushort4*)&xl[pi]) = l;
    }

    // ---- runtime n_act from bias_mask (prefix-active structure) ----
    if (wvid < 4) {
        float bv = bmask[n * D_DIM + wvid * 64 + lane];
        unsigned long long actm = __ballot(bv != 0.0f);
        if (lane == 0) s_cnt[wvid] = __popcll(actm);
    }

    // ---- per-lane masked bias: j = (wvid + 8u)*16 + quad*4 + rg ----
    float bias_r[2][4];
    #pragma unroll
    for (int u = 0; u < 2; ++u)
        #pragma unroll
        for (int rg = 0; rg < 4; ++rg) {
            int c = (wvid + 8 * u) * 16 + quad * 4 + rg;
            bias_r[u][rg] = braw[n * D_DIM + c] * bmask[n * D_DIM + c];
        }

    float bmj[2];   // ONFLY: w-row (j) mask scalar per owned j-tile
    if (ONFLY) {
        #pragma unroll
        for (int u = 0; u < 2; ++u)
            bmj[u] = bmask[n * D_DIM + (wvid + 8 * u) * 16 + l16];
    }

    // w-fragment base: lane covers w[j = (wvid+8u)*16 + l16][i = kt*32 + quad*8 .. +7]
    const size_t wbase = ((size_t)n * D_DIM + (size_t)wvid * 16 + l16) * D_DIM + (size_t)quad * 8;
    const size_t ustride = (size_t)128 * D_DIM;   // 8 j-tiles * 16 rows

    __syncthreads();

    const int n_act  = s_cnt[0] + s_cnt[1] + s_cnt[2] + s_cnt[3];   // {128..256}, mult of 32
    const int kt_lim = n_act >> 5;                                   // active k-tiles (4..8)
    const int njt    = n_act >> 4;                                   // active j-tiles (8..16)
    const bool u1a   = (wvid + 8) < njt;                             // second tile active?

    // Named double buffers (STATIC indexing only — no arrays indexed by kt&1)
    short8 whA[2], wlA[2], whB[2], wlB[2];

    auto loadW = [&](int kt, short8* h, short8* l) {
        size_t off = wbase + (size_t)(kt << 5);
        h[0] = *((const short8*)(w_hi + off));
        l[0] = *((const short8*)(w_lo + off));
        if (u1a) {
            h[1] = *((const short8*)(w_hi + off + ustride));
            l[1] = *((const short8*)(w_lo + off + ustride));
        }
    };

    if (!ONFLY) loadW(0, whA, wlA);   // prologue prefetch for step 0

    #pragma unroll 1
    for (int step = 0; step < NSTEPS; ++step) {
        f32x4 acc[2][4];   // [u][bt]: D[j=(wvid+8u)*16+quad*4+rg][b=bt*16+l16]
        #pragma unroll
        for (int u = 0; u < 2; ++u)
            #pragma unroll
            for (int bt = 0; bt < 4; ++bt)
                acc[u][bt] = f32x4{0.f, 0.f, 0.f, 0.f};

        auto compute = [&](int kt, const short8* wh, const short8* wl) {
            const int c0 = kt * 32 + quad * 8;
            #pragma unroll
            for (int bt = 0; bt < 4; ++bt) {
                int m  = bt * 16 + l16;
                int pi = m * 256 + ((((c0 >> 3) ^ (m & 7))) << 3);
                short8 x8h = *((const short8*)&xh[pi]);
                short8 x8l = *((const short8*)&xl[pi]);
                acc[0][bt] = __builtin_amdgcn_mfma_f32_16x16x32_bf16(wh[0], x8h, acc[0][bt], 0, 0, 0);
                acc[0][bt] = __builtin_amdgcn_mfma_f32_16x16x32_bf16(wh[0], x8l, acc[0][bt], 0, 0, 0);
                acc[0][bt] = __builtin_amdgcn_mfma_f32_16x16x32_bf16(wl[0], x8h, acc[0][bt], 0, 0, 0);
                if (u1a) {
                    acc[1][bt] = __builtin_amdgcn_mfma_f32_16x16x32_bf16(wh[1], x8h, acc[1][bt], 0, 0, 0);
                    acc[1][bt] = __builtin_amdgcn_mfma_f32_16x16x32_bf16(wh[1], x8l, acc[1][bt], 0, 0, 0);
                    acc[1][bt] = __builtin_amdgcn_mfma_f32_16x16x32_bf16(wl[1], x8h, acc[1][bt], 0, 0, 0);
                }
            }
        };

        if (!ONFLY) {
            // Software-pipelined pairwise k-loop: prefetch kt+1 into the idle
            // buffer while MFMA consumes the ready one.
            int kt = 0;
            for (; kt + 2 <= kt_lim; kt += 2) {
                loadW(kt + 1, whB, wlB);                       // always in-bounds
                compute(kt, whA, wlA);
                int k2 = kt + 2;
                loadW(k2 < kt_lim ? k2 : kt + 1, whA, wlA);    // clamped (dup harmless)
                compute(kt + 1, whB, wlB);
            }
            if (kt < kt_lim) compute(kt, whA, wlA);            // odd remainder (uses A)
            // Prefetch next step's kt=0 now — latency hides under the epilogue.
            loadW(0, whA, wlA);
        } else {
            // Fallback: mask+split W from fp32 on the fly (no workspace).
            for (int kt = 0; kt < kt_lim; ++kt) {
                const float* bmi_p = bmask + n * D_DIM + kt * 32 + quad * 8;
                float4 mi0 = ((const float4*)bmi_p)[0];
                float4 mi1 = ((const float4*)bmi_p)[1];
                float mi[8] = {mi0.x, mi0.y, mi0.z, mi0.w, mi1.x, mi1.y, mi1.z, mi1.w};
                #pragma unroll
                for (int u = 0; u < 2; ++u) if (u == 0 || u1a) {
                    const float* wp = wraw + wbase + (size_t)u * ustride + (size_t)(kt << 5);
                    float4 w0 = ((const float4*)wp)[0];
                    float4 w1 = ((const float4*)wp)[1];
                    float wvv[8] = {w0.x, w0.y, w0.z, w0.w, w1.x, w1.y, w1.z, w1.w};
                    #pragma unroll
                    for (int j = 0; j < 8; ++j) {
                        unsigned short h, l;
                        split2(wvv[j] * bmj[u] * mi[j], h, l);
                        whA[u][j] = (short)h;
                        wlA[u][j] = (short)l;
                    }
                }
                compute(kt, whA, wlA);
            }
        }

        __syncthreads();   // all waves' x-reads done before x is overwritten

        const bool last = (step == NSTEPS - 1);
        #pragma unroll
        for (int u = 0; u < 2; ++u) {
            const bool act = (u == 0) || u1a;
            if (act || last) {
                #pragma unroll
                for (int bt = 0; bt < 4; ++bt) {
                    int r  = bt * 16 + l16;                       // batch row
                    int c0 = (wvid + 8 * u) * 16 + quad * 4;      // 4 consecutive cols
                    int pi = r * 256 + ((((c0 >> 3) ^ (r & 7))) << 3) + (c0 & 7);
                    ushort4 oh = *((const ushort4*)&xh[pi]);      // ds_read_b64
                    ushort4 ol = *((const ushort4*)&xl[pi]);
                    float xn[4];
                    xn[0] = bf16_to_f(oh.x) + bf16_to_f(ol.x);
                    xn[1] = bf16_to_f(oh.y) + bf16_to_f(ol.y);
                    xn[2] = bf16_to_f(oh.z) + bf16_to_f(ol.z);
                    xn[3] = bf16_to_f(oh.w) + bf16_to_f(ol.w);
                    if (act) {
                        #pragma unroll
                        for (int rg = 0; rg < 4; ++rg)
                            xn[rg] += fmaxf(acc[u][bt][rg] + bias_r[u][rg], 0.f);
                    }
                    if (last) {
                        float4 o;
                        o.x = xn[0]; o.y = xn[1]; o.z = xn[2]; o.w = xn[3];
                        *((float4*)(xdst + (size_t)r * row_stride + c0)) = o;  // dwordx4
                    } else if (act) {
                        ushort4 h, l;
                        split2(xn[0], h.x, l.x);
                        split2(xn[1], h.y, l.y);
                        split2(xn[2], h.z, l.z);
                        split2(xn[3], h.w, l.w);
                        *((ushort4*)&xh[pi]) = h;                 // ds_write_b64
                        *((ushort4*)&xl[pi]) = l;
                    }
                }
            }
        }
        __syncthreads();   // new x fully written before next step's reads
    }
}

// ---------------------------------------------------------------------------
extern "C" void kernel_launch(void* const* d_in, const int* in_sizes, int n_in,
                              void* d_out, int out_size, void* d_ws, size_t ws_size,
                              hipStream_t stream) {
    const float* x  = (const float*)d_in[0];
    const float* w  = (const float*)d_in[1];
    const float* b  = (const float*)d_in[2];
    const float* wm = (const float*)d_in[3];
    const float* bm = (const float*)d_in[4];
    float* out = (float*)d_out;

    const size_t needW = (size_t)2 * N_LIN * D_DIM * D_DIM * sizeof(unsigned short); // 16 MB
    const int grid = (B_TOT / BT) * N_LIN;   // 2048 blocks

    if (ws_size >= needW) {
        // Fast path: pre-split masked weights into workspace once per call.
        unsigned short* w_hi = (unsigned short*)d_ws;
        unsigned short* w_lo = w_hi + (size_t)N_LIN * D_DIM * D_DIM;
        prep_kernel<<<1024, 256, 0, stream>>>(w, wm, w_hi, w_lo);
        fused_kernel<false><<<grid, 512, 0, stream>>>(x, w_hi, w_lo, w, wm, b, bm, out);
    } else {
        // Fallback: no scratch — mask+split W on the fly inside the kernel.
        fused_kernel<true><<<grid, 512, 0, stream>>>(x, nullptr, nullptr, w, wm, b, bm, out);
    }
}